// Round 1
// baseline (323.626 us; speedup 1.0000x reference)
//
#include <hip/hip_runtime.h>

#define N_NODES 100000
#define N_EDGES 1200000
#define NF 64

typedef __attribute__((ext_vector_type(8))) short short8;
typedef __attribute__((ext_vector_type(4))) float float4v;

__device__ __forceinline__ ushort f2bf(float f) {
    unsigned u = __float_as_uint(f);
    return (ushort)((u + 0x7FFF + ((u >> 16) & 1)) >> 16);  // RNE
}

// binning: bin = node >> 9, 196 bins of 512 nodes, fixed capacity per bin
#define NBINS 196
#define CAP 7680                 // max used ~6420 + pads ~800 + 16 tail < 7680

// ---------------- workspace layout (bytes), flat (~36 MB of 268 MB)
#define OFF_CNT    0             // int[100000]  non-self in-degree (dst)
#define OFF_ENDP   400128        // int[100000]
#define OFF_DEG    800256        // int[100000]  non-self out-degree (src)
#define OFF_WCUR   1200384       // int[100000]  scatter cursors
#define OFF_PKW    1600512       // ushort[2*1024*8] = 32 KB packed B-fragments
#define OFF_SRCS   1633280       // int[196*7680]    = 6.02 MB (final, dst-binned)
#define OFF_NRMS   7654400       // ushort[196*7680] = 3.01 MB
#define OFF_EMBBF  10664960      // ushort[6.4M] = 12.8 MB
#define OFF_HBF    23464960     // ushort[6.4M] = 12.8 MB -> ends 36,264,960

// blocks 0-7: pack W into B-fragment order; blocks 8+: emb f32 -> bf16
// plus zero-init of deg/cnt (32+32 ints per emb block, exact cover)
__global__ __launch_bounds__(256) void prep(const float* __restrict__ W10,
                                            const float* __restrict__ W11,
                                            const float* __restrict__ W20,
                                            const float* __restrict__ W21,
                                            ushort* __restrict__ pk,
                                            const float* __restrict__ emb,
                                            ushort* __restrict__ emb_bf,
                                            int* __restrict__ deg,
                                            int* __restrict__ cnt) {
    int b = blockIdx.x;
    int t = threadIdx.x;
    if (b < 8) {
        int idx = b * 256 + t;   // [0, 2048)
        int layer = idx >> 10;
        int rest = idx & 1023;
        int f = rest >> 6, L = rest & 63;
        int n = (f & 3) * 16 + (L & 15);
        int kb = (f >> 2) * 32 + ((L >> 4) << 3);
#pragma unroll
        for (int j = 0; j < 8; ++j) {
            int k = kb + j;
            const float* W = layer ? ((k < 64) ? W20 : W21) : ((k < 64) ? W10 : W11);
            pk[idx * 8 + j] = f2bf(W[(k & 63) * 64 + n]);
        }
    } else {
        int bb = b - 8;          // [0, 3125)
        int i = (bb * 256 + t) * 8;
        float4 v0 = *(const float4*)(emb + i);
        float4 v1 = *(const float4*)(emb + i + 4);
        uint4 o;
        o.x = (uint)f2bf(v0.x) | ((uint)f2bf(v0.y) << 16);
        o.y = (uint)f2bf(v0.z) | ((uint)f2bf(v0.w) << 16);
        o.z = (uint)f2bf(v1.x) | ((uint)f2bf(v1.y) << 16);
        o.w = (uint)f2bf(v1.z) | ((uint)f2bf(v1.w) << 16);
        *(uint4*)(emb_bf + i) = o;
        int z = bb * 32;
        if (t < 32) deg[z + t] = 0;
        else if (t < 64) cnt[z + t - 32] = 0;
    }
}

// 1 pass over edges: fire-and-forget degree atomics (replaces LDS hists + binD1)
#define E4 (N_EDGES / 4)         // 300000
#define EBLK ((E4 + 255) / 256)  // 1172
__global__ __launch_bounds__(256) void count_edges(const int* __restrict__ row,
                                                   const int* __restrict__ col,
                                                   int* __restrict__ deg,
                                                   int* __restrict__ cnt) {
    int i4 = blockIdx.x * 256 + threadIdx.x;
    if (i4 >= E4) return;
    int4 rs = ((const int4*)row)[i4];
    int4 cs = ((const int4*)col)[i4];
    if (rs.x != cs.x) { atomicAdd(&deg[rs.x], 1); atomicAdd(&cnt[cs.x], 1); }
    if (rs.y != cs.y) { atomicAdd(&deg[rs.y], 1); atomicAdd(&cnt[cs.y], 1); }
    if (rs.z != cs.z) { atomicAdd(&deg[rs.z], 1); atomicAdd(&cnt[cs.z], 1); }
    if (rs.w != cs.w) { atomicAdd(&deg[rs.w], 1); atomicAdd(&cnt[cs.w], 1); }
}

// per dst-bin: scan of 4-aligned counts -> endp/wcur + pad/tail zero-fill.
// No edge-data pass (cnt already computed globally).
__global__ __launch_bounds__(512) void scan_bins(const int* __restrict__ cnt,
                                                 int* __restrict__ endp,
                                                 int* __restrict__ wcur,
                                                 int* __restrict__ srcs,
                                                 ushort* __restrict__ nrms) {
    __shared__ int hist[512];
    __shared__ int tot_s;
    int t = threadIdx.x;
    int b = blockIdx.x;
    int start = b * CAP;
    int n0 = (b << 9) + t;
    int o0 = (n0 < N_NODES) ? cnt[n0] : 0;
    int A0 = (o0 + 3) & ~3;
    hist[t] = A0;
    __syncthreads();
    for (int off = 1; off < 512; off <<= 1) {
        int v = (t >= off) ? hist[t - off] : 0;
        __syncthreads();
        hist[t] += v;
        __syncthreads();
    }
    int e0 = hist[t] - A0;   // exclusive (aligned)
    if (t == 511) tot_s = hist[511];
    if (n0 < N_NODES) { endp[n0] = start + e0 + o0; wcur[n0] = start + e0; }
    // zero-fill per-node alignment pads
    for (int k = o0; k < A0; ++k) { srcs[start + e0 + k] = 0; nrms[start + e0 + k] = 0; }
    __syncthreads();
    // zero-fill 16-slot bin tail (layer's straight-line 2x8 chunks may overread)
    if (t < 16) { srcs[start + tot_s + t] = 0; nrms[start + tot_s + t] = 0; }
}

// 2nd pass over edges: direct scatter into final CSR slots, nrm on the fly
__global__ __launch_bounds__(256) void scatter_edges(const int* __restrict__ row,
                                                     const int* __restrict__ col,
                                                     const int* __restrict__ deg,
                                                     int* __restrict__ wcur,
                                                     int* __restrict__ srcs,
                                                     ushort* __restrict__ nrms) {
    int i4 = blockIdx.x * 256 + threadIdx.x;
    if (i4 >= E4) return;
    int4 rs = ((const int4*)row)[i4];
    int4 cs = ((const int4*)col)[i4];
#pragma unroll
    for (int j = 0; j < 4; ++j) {
        int s = (j == 0) ? rs.x : (j == 1) ? rs.y : (j == 2) ? rs.z : rs.w;
        int d = (j == 0) ? cs.x : (j == 1) ? cs.y : (j == 2) ? cs.z : cs.w;
        if (s != d) {
            int slot = atomicAdd(&wcur[d], 1);
            int dgs = deg[s];                 // >=1 (this edge was counted)
            int dgd = deg[d];
            float nrm = -rsqrtf((float)dgs) * (dgd ? rsqrtf((float)dgd) : 0.0f);
            srcs[slot] = s;
            nrms[slot] = f2bf(nrm);
        }
    }
}

// Fused layer: 16 nodes/wave; 4 edges/gather-instr (quarter-wave per edge,
// 4 features/lane). PAIR-INTERLEAVED: two nodes' chunks issue back-to-back
// (24 vmem in flight) before either node's reduce chain.  (UNCHANGED)
#define NPW 16
#define WPB 2
#define NPB (NPW * WPB)                       // 32
#define LB2 ((N_NODES + NPB - 1) / NPB)       // 3125

__global__ __launch_bounds__(128, 8) void cheb_layer(const ushort* __restrict__ x,
                                                     const int* __restrict__ srcs,
                                                     const ushort* __restrict__ nrms,
                                                     const int* __restrict__ endp,
                                                     const int* __restrict__ cnt,
                                                     const ushort* __restrict__ pk,
                                                     const float* __restrict__ bias,
                                                     ushort* __restrict__ out_bf,
                                                     float* __restrict__ out_f32,
                                                     int last) {
    __shared__ ushort sA[WPB][16][136];   // 8.7 KB

    int t = threadIdx.x;
    int lane = t & 63, wid = t >> 6;
    int c = lane & 15, q = lane >> 4;
    int qd = q, fg = c;
    int nb = blockIdx.x * NPB + wid * NPW;

    int nend = 0, ncnt = 0;
    if (lane < NPW && nb + lane < N_NODES) {
        nend = endp[nb + lane];
        ncnt = cnt[nb + lane];
    }

    const uint2* xr = (const uint2*)x;   // row = 16 uint2 (64 bf16)

    auto chunk8 = [&](int eb, int eendL, float& a0, float& a1, float& a2, float& a3) {
        int4 sv = *(const int4*)(srcs + eb);       // edges eb..eb+3 (uniform)
        int4 sw = *(const int4*)(srcs + eb + 4);   // edges eb+4..eb+7
        uint2 nv = *(const uint2*)(nrms + eb);
        uint2 nw = *(const uint2*)(nrms + eb + 4);
        int sA01 = (qd & 1) ? sv.y : sv.x;
        int sA23 = (qd & 1) ? sv.w : sv.z;
        int srcA = (qd & 2) ? sA23 : sA01;
        int sB01 = (qd & 1) ? sw.y : sw.x;
        int sB23 = (qd & 1) ? sw.w : sw.z;
        int srcB = (qd & 2) ? sB23 : sB01;
        uint nAp = (qd & 2) ? nv.y : nv.x;
        uint nBp = (qd & 2) ? nw.y : nw.x;
        float nAf = __uint_as_float((qd & 1) ? (nAp & 0xffff0000u) : (nAp << 16));
        float nBf = __uint_as_float((qd & 1) ? (nBp & 0xffff0000u) : (nBp << 16));
        nAf = (eb + qd < eendL) ? nAf : 0.0f;
        nBf = (eb + 4 + qd < eendL) ? nBf : 0.0f;
        uint2 gA = xr[(size_t)srcA * 16 + fg];
        uint2 gB = xr[(size_t)srcB * 16 + fg];
        a0 = fmaf(nAf, __uint_as_float(gA.x << 16), a0);
        a1 = fmaf(nAf, __uint_as_float(gA.x & 0xffff0000u), a1);
        a2 = fmaf(nAf, __uint_as_float(gA.y << 16), a2);
        a3 = fmaf(nAf, __uint_as_float(gA.y & 0xffff0000u), a3);
        a0 = fmaf(nBf, __uint_as_float(gB.x << 16), a0);
        a1 = fmaf(nBf, __uint_as_float(gB.x & 0xffff0000u), a1);
        a2 = fmaf(nBf, __uint_as_float(gB.y << 16), a2);
        a3 = fmaf(nBf, __uint_as_float(gB.y & 0xffff0000u), a3);
    };

#pragma unroll
    for (int gp = 0; gp < NPW; gp += 2) {
        int cn0 = __builtin_amdgcn_readlane(ncnt, gp);
        int ee0 = __builtin_amdgcn_readlane(nend, gp);
        int cn1 = __builtin_amdgcn_readlane(ncnt, gp + 1);
        int ee1 = __builtin_amdgcn_readlane(nend, gp + 1);
        int s0 = ee0 - cn0, s1 = ee1 - cn1;   // 4-aligned starts
        float a0 = 0, a1 = 0, a2 = 0, a3 = 0;
        float b0 = 0, b1 = 0, b2 = 0, b3 = 0;

        // static 2x8-edge chunks per node, pair-interleaved (masked; safe via tail)
        chunk8(s0,     ee0, a0, a1, a2, a3);
        chunk8(s1,     ee1, b0, b1, b2, b3);
        chunk8(s0 + 8, ee0, a0, a1, a2, a3);
        chunk8(s1 + 8, ee1, b0, b1, b2, b3);
        // rare heavy nodes (cn > 16)
        for (int e = s0 + 16; e < ee0; e += 8) chunk8(e, ee0, a0, a1, a2, a3);
        for (int e = s1 + 16; e < ee1; e += 8) chunk8(e, ee1, b0, b1, b2, b3);

        // interleaved cross-quarter reductions for both nodes
        a0 += __shfl_xor(a0, 16, 64); b0 += __shfl_xor(b0, 16, 64);
        a1 += __shfl_xor(a1, 16, 64); b1 += __shfl_xor(b1, 16, 64);
        a2 += __shfl_xor(a2, 16, 64); b2 += __shfl_xor(b2, 16, 64);
        a3 += __shfl_xor(a3, 16, 64); b3 += __shfl_xor(b3, 16, 64);
        a0 += __shfl_xor(a0, 32, 64); b0 += __shfl_xor(b0, 32, 64);
        a1 += __shfl_xor(a1, 32, 64); b1 += __shfl_xor(b1, 32, 64);
        a2 += __shfl_xor(a2, 32, 64); b2 += __shfl_xor(b2, 32, 64);
        a3 += __shfl_xor(a3, 32, 64); b3 += __shfl_xor(b3, 32, 64);

        int node0 = nb + gp, node1 = nb + gp + 1;
        int ni0 = (node0 < N_NODES) ? node0 : 0;
        int ni1 = (node1 < N_NODES) ? node1 : 0;
        if (qd == 0) {
            uint2 xv0 = xr[(size_t)ni0 * 16 + fg];
            uint2 xv1 = xr[(size_t)ni1 * 16 + fg];
            *(uint2*)&sA[wid][gp][4 * fg] = xv0;
            *(uint2*)&sA[wid][gp + 1][4 * fg] = xv1;
        }
        if (qd == 1) {
            uint2 p0, p1;
            p0.x = (uint)f2bf(a0) | ((uint)f2bf(a1) << 16);
            p0.y = (uint)f2bf(a2) | ((uint)f2bf(a3) << 16);
            p1.x = (uint)f2bf(b0) | ((uint)f2bf(b1) << 16);
            p1.y = (uint)f2bf(b2) | ((uint)f2bf(b3) << 16);
            *(uint2*)&sA[wid][gp][64 + 4 * fg] = p0;
            *(uint2*)&sA[wid][gp + 1][64 + 4 * fg] = p1;
        }
    }
    __builtin_amdgcn_wave_barrier();

    const short8* pk8 = (const short8*)pk;
    float4v C[4];
#pragma unroll
    for (int nt = 0; nt < 4; ++nt) {
        float b = bias[nt * 16 + c];
        C[nt] = (float4v){b, b, b, b};
    }
#pragma unroll
    for (int kt = 0; kt < 4; ++kt) {
        short8 af = *(const short8*)&sA[wid][c][kt * 32 + q * 8];
#pragma unroll
        for (int nt = 0; nt < 4; ++nt) {
            short8 bfr = pk8[(kt * 4 + nt) * 64 + lane];
            C[nt] = __builtin_amdgcn_mfma_f32_16x16x32_bf16(af, bfr, C[nt], 0, 0, 0);
        }
    }

#pragma unroll
    for (int nt = 0; nt < 4; ++nt) {
#pragma unroll
        for (int i = 0; i < 4; ++i) {
            int node = nb + q * 4 + i;
            if (node < N_NODES) {
                float v = C[nt][i];
                if (!last) {
                    v = fmaxf(v, 0.0f);
                    out_bf[(size_t)node * NF + nt * 16 + c] = f2bf(v);
                } else {
                    out_f32[(size_t)node * NF + nt * 16 + c] = v;
                }
            }
        }
    }
}

extern "C" void kernel_launch(void* const* d_in, const int* in_sizes, int n_in,
                              void* d_out, int out_size, void* d_ws, size_t ws_size,
                              hipStream_t stream) {
    const int* ei = (const int*)d_in[0];
    const int* row = ei;
    const int* col = ei + N_EDGES;
    const float* emb = (const float*)d_in[1];
    const float* W1_0 = (const float*)d_in[2];
    const float* W1_1 = (const float*)d_in[3];
    const float* b1 = (const float*)d_in[4];
    const float* W2_0 = (const float*)d_in[5];
    const float* W2_1 = (const float*)d_in[6];
    const float* b2 = (const float*)d_in[7];
    float* out = (float*)d_out;

    char* ws = (char*)d_ws;
    int* cnt = (int*)(ws + OFF_CNT);
    int* endp = (int*)(ws + OFF_ENDP);
    int* deg = (int*)(ws + OFF_DEG);
    int* wcur = (int*)(ws + OFF_WCUR);
    ushort* pk = (ushort*)(ws + OFF_PKW);
    int* srcs = (int*)(ws + OFF_SRCS);
    ushort* nrms = (ushort*)(ws + OFF_NRMS);
    ushort* emb_bf = (ushort*)(ws + OFF_EMBBF);
    ushort* h_bf = (ushort*)(ws + OFF_HBF);

    prep<<<8 + 3125, 256, 0, stream>>>(W1_0, W1_1, W2_0, W2_1, pk, emb, emb_bf, deg, cnt);
    count_edges<<<EBLK, 256, 0, stream>>>(row, col, deg, cnt);
    scan_bins<<<NBINS, 512, 0, stream>>>(cnt, endp, wcur, srcs, nrms);
    scatter_edges<<<EBLK, 256, 0, stream>>>(row, col, deg, wcur, srcs, nrms);

    cheb_layer<<<LB2, 128, 0, stream>>>(emb_bf, srcs, nrms, endp, cnt, pk, b1, h_bf, nullptr, 0);
    cheb_layer<<<LB2, 128, 0, stream>>>(h_bf, srcs, nrms, endp, cnt, pk + 8192, b2, nullptr, out, 1);
}

// Round 2
// 203.428 us; speedup vs baseline: 1.5909x; 1.5909x over previous
//
#include <hip/hip_runtime.h>

#define N_NODES 100000
#define N_EDGES 1200000
#define NF 64

typedef __attribute__((ext_vector_type(8))) short short8;
typedef __attribute__((ext_vector_type(4))) float float4v;

__device__ __forceinline__ ushort f2bf(float f) {
    unsigned u = __float_as_uint(f);
    return (ushort)((u + 0x7FFF + ((u >> 16) & 1)) >> 16);  // RNE
}

// binning: bin = node >> 9, 196 bins of 512 nodes, fixed capacity per bin
#define NBINS 196
#define CAP 7680                 // max used ~6420 + pads ~800 + 16 tail < 7680
#define EPB 2560
#define NBLK 469                 // ceil(1200000/2560)

// ---------------- workspace layout (bytes), flat (~42 MB of 268 MB)
#define OFF_CNT    0             // int[100000]
#define OFF_ENDP   400128        // int[100000]
#define OFF_DINV   800256        // float[100000]
#define OFF_CUR    1200384       // int[392] bin-relative cursors (memset to 0)
#define OFF_PKW    1202048       // ushort[2*1024*8] = 32 KB packed B-fragments
#define OFF_SRCS   1234816       // int[196*7680]    = 6.02 MB (final, dst-binned)
#define OFF_SBIN   7255936       // ushort[196*7680] = 3.01 MB staging
#define OFF_DBIN   10266496     // int[196*7680]    = 6.02 MB staging
#define OFF_EMBBF  16287616     // ushort[6.4M] = 12.8 MB
#define OFF_HBF    29087616     // ushort[6.4M] = 12.8 MB -> ends 41,887,616

// Fused: blocks [0,469) binsort (long pole, dispatched first);
//        blocks [469,477) W-pack; blocks [477, 477+3125) emb f32->bf16.
// cur[] is BIN-RELATIVE (zeroed by hipMemsetAsync before this launch).
__global__ __launch_bounds__(256) void prepsort(const float* __restrict__ W10,
                                                const float* __restrict__ W11,
                                                const float* __restrict__ W20,
                                                const float* __restrict__ W21,
                                                ushort* __restrict__ pk,
                                                const float* __restrict__ emb,
                                                ushort* __restrict__ emb_bf,
                                                const int* __restrict__ row,
                                                const int* __restrict__ col,
                                                int* __restrict__ cur,
                                                ushort* __restrict__ sbinned,
                                                int* __restrict__ dbinned) {
    int b = blockIdx.x;
    int t = threadIdx.x;
    if (b < NBLK) {
        // ---- binsort: LDS hist -> chunk reservation -> scatter
        __shared__ int2 ecache[EPB];               // 20 KB
        __shared__ int sh[NBINS], dh[NBINS];
        __shared__ int sbase[NBINS], dbase[NBINS];
        if (t < NBINS) { sh[t] = 0; dh[t] = 0; }
        __syncthreads();
        int base = b * EPB;
        for (int k = 0; k < EPB / 256; ++k) {
            int e = base + k * 256 + t;
            int s = -1, d = -1;
            if (e < N_EDGES) { s = row[e]; d = col[e]; }
            ecache[k * 256 + t] = make_int2(s, d);
            if (s >= 0 && s != d) {
                atomicAdd(&sh[s >> 9], 1);
                atomicAdd(&dh[d >> 9], 1);
            }
        }
        __syncthreads();
        if (t < NBINS) {
            sbase[t] = t * CAP + atomicAdd(&cur[t], sh[t]);
            dbase[t] = t * CAP + atomicAdd(&cur[NBINS + t], dh[t]);
        }
        __syncthreads();
        for (int k = 0; k < EPB / 256; ++k) {
            int2 p = ecache[k * 256 + t];
            int s = p.x, d = p.y;
            if (s >= 0 && s != d) {
                int ss = atomicAdd(&sbase[s >> 9], 1);
                sbinned[ss] = (ushort)(s & 511);
                int ds = atomicAdd(&dbase[d >> 9], 1);
                dbinned[ds] = (s << 9) | (d & 511);
            }
        }
    } else if (b < NBLK + 8) {
        int idx = (b - NBLK) * 256 + t;   // [0, 2048)
        int layer = idx >> 10;
        int rest = idx & 1023;
        int f = rest >> 6, L = rest & 63;
        int n = (f & 3) * 16 + (L & 15);
        int kb = (f >> 2) * 32 + ((L >> 4) << 3);
#pragma unroll
        for (int j = 0; j < 8; ++j) {
            int k = kb + j;
            const float* W = layer ? ((k < 64) ? W20 : W21) : ((k < 64) ? W10 : W11);
            pk[idx * 8 + j] = f2bf(W[(k & 63) * 64 + n]);
        }
    } else {
        int bb = b - NBLK - 8;            // [0, 3125)
        int i = (bb * 256 + t) * 8;
        float4 v0 = *(const float4*)(emb + i);
        float4 v1 = *(const float4*)(emb + i + 4);
        uint4 o;
        o.x = (uint)f2bf(v0.x) | ((uint)f2bf(v0.y) << 16);
        o.y = (uint)f2bf(v0.z) | ((uint)f2bf(v0.w) << 16);
        o.z = (uint)f2bf(v1.x) | ((uint)f2bf(v1.y) << 16);
        o.w = (uint)f2bf(v1.z) | ((uint)f2bf(v1.w) << 16);
        *(uint4*)(emb_bf + i) = o;
    }
}

// Fused binD1 + binD2 (independent now that nrms is gone):
// blocks [0,196): per src-bin hist -> dinv
// blocks [196,392): per dst-bin single-pass (LDS edge cache) hist+scan+scatter
__global__ __launch_bounds__(512) void build(const ushort* __restrict__ sbinned,
                                             const int* __restrict__ dbinned,
                                             const int* __restrict__ cur,
                                             float* __restrict__ dinv,
                                             int* __restrict__ cnt,
                                             int* __restrict__ endp,
                                             int* __restrict__ srcs) {
    int t = threadIdx.x;
    int b = blockIdx.x;
    if (b < NBINS) {
        __shared__ int hist[512];
        hist[t] = 0;
        __syncthreads();
        int start = b * CAP;
        int end = start + cur[b];
        for (int i = start + t; i < end; i += 512)
            atomicAdd(&hist[sbinned[i]], 1);
        __syncthreads();
        int n0 = (b << 9) + t;
        if (n0 < N_NODES) dinv[n0] = hist[t] ? rsqrtf((float)hist[t]) : 0.0f;
    } else {
        int bb = b - NBINS;
        __shared__ int ecache[CAP];           // 30 KB: whole bin cached once
        __shared__ int hist[512];
        __shared__ int lcur[512];
        __shared__ int tot_s;
        hist[t] = 0;
        __syncthreads();
        int start = bb * CAP;
        int len = cur[NBINS + bb];
        for (int i = t; i < len; i += 512) {
            int p = dbinned[start + i];
            ecache[i] = p;
            atomicAdd(&hist[p & 511], 1);
        }
        __syncthreads();
        int o0 = hist[t];
        int A0 = (o0 + 3) & ~3;
        __syncthreads();
        hist[t] = A0;
        __syncthreads();
        for (int off = 1; off < 512; off <<= 1) {
            int v = (t >= off) ? hist[t - off] : 0;
            __syncthreads();
            hist[t] += v;
            __syncthreads();
        }
        int e0 = hist[t] - A0;   // exclusive (aligned)
        if (t == 511) tot_s = hist[511];
        lcur[t] = start + e0;
        int n0 = (bb << 9) + t;
        if (n0 < N_NODES) { cnt[n0] = o0; endp[n0] = start + e0 + o0; }
        __syncthreads();
        for (int i = t; i < len; i += 512) {
            int p = ecache[i];
            int slot = atomicAdd(&lcur[p & 511], 1);
            srcs[slot] = p >> 9;
        }
        __syncthreads();
        // zero-fill per-node alignment pads (address-safety for int4 overreads)
        for (int k = o0; k < A0; ++k) srcs[start + e0 + k] = 0;
        // zero-fill 16-slot bin tail (layer's straight-line 2x8 chunks may overread)
        if (t < 16) srcs[start + tot_s + t] = 0;
    }
}

// Fused layer: 16 nodes/wave; 4 edges/gather-instr (quarter-wave per edge,
// 4 features/lane). PAIR-INTERLEAVED: two nodes' chunks issue back-to-back
// before either node's reduce chain. Norms now on-the-fly: accumulate
// dinv[s]*x per edge (dinv is L2-resident f32), scale by -dinv[dst] ONCE
// per node after the reduction (distributivity).
#define NPW 16
#define WPB 2
#define NPB (NPW * WPB)                       // 32
#define LB2 ((N_NODES + NPB - 1) / NPB)       // 3125

__global__ __launch_bounds__(128, 8) void cheb_layer(const ushort* __restrict__ x,
                                                     const int* __restrict__ srcs,
                                                     const float* __restrict__ dinv,
                                                     const int* __restrict__ endp,
                                                     const int* __restrict__ cnt,
                                                     const ushort* __restrict__ pk,
                                                     const float* __restrict__ bias,
                                                     ushort* __restrict__ out_bf,
                                                     float* __restrict__ out_f32,
                                                     int last) {
    __shared__ ushort sA[WPB][16][136];   // 8.7 KB

    int t = threadIdx.x;
    int lane = t & 63, wid = t >> 6;
    int c = lane & 15, q = lane >> 4;
    int qd = q, fg = c;
    int nb = blockIdx.x * NPB + wid * NPW;

    int nend = 0, ncnt = 0;
    if (lane < NPW && nb + lane < N_NODES) {
        nend = endp[nb + lane];
        ncnt = cnt[nb + lane];
    }

    const uint2* xr = (const uint2*)x;   // row = 16 uint2 (64 bf16)

    auto chunk8 = [&](int eb, int eendL, float& a0, float& a1, float& a2, float& a3) {
        int4 sv = *(const int4*)(srcs + eb);       // edges eb..eb+3 (uniform)
        int4 sw = *(const int4*)(srcs + eb + 4);   // edges eb+4..eb+7
        int sA01 = (qd & 1) ? sv.y : sv.x;
        int sA23 = (qd & 1) ? sv.w : sv.z;
        int srcA = (qd & 2) ? sA23 : sA01;
        int sB01 = (qd & 1) ? sw.y : sw.x;
        int sB23 = (qd & 1) ? sw.w : sw.z;
        int srcB = (qd & 2) ? sB23 : sB01;
        float nAf = dinv[srcA];                    // broadcast within quarter
        float nBf = dinv[srcB];
        nAf = (eb + qd < eendL) ? nAf : 0.0f;
        nBf = (eb + 4 + qd < eendL) ? nBf : 0.0f;
        uint2 gA = xr[(size_t)srcA * 16 + fg];
        uint2 gB = xr[(size_t)srcB * 16 + fg];
        a0 = fmaf(nAf, __uint_as_float(gA.x << 16), a0);
        a1 = fmaf(nAf, __uint_as_float(gA.x & 0xffff0000u), a1);
        a2 = fmaf(nAf, __uint_as_float(gA.y << 16), a2);
        a3 = fmaf(nAf, __uint_as_float(gA.y & 0xffff0000u), a3);
        a0 = fmaf(nBf, __uint_as_float(gB.x << 16), a0);
        a1 = fmaf(nBf, __uint_as_float(gB.x & 0xffff0000u), a1);
        a2 = fmaf(nBf, __uint_as_float(gB.y << 16), a2);
        a3 = fmaf(nBf, __uint_as_float(gB.y & 0xffff0000u), a3);
    };

#pragma unroll
    for (int gp = 0; gp < NPW; gp += 2) {
        int cn0 = __builtin_amdgcn_readlane(ncnt, gp);
        int ee0 = __builtin_amdgcn_readlane(nend, gp);
        int cn1 = __builtin_amdgcn_readlane(ncnt, gp + 1);
        int ee1 = __builtin_amdgcn_readlane(nend, gp + 1);
        int s0 = ee0 - cn0, s1 = ee1 - cn1;   // 4-aligned starts
        float a0 = 0, a1 = 0, a2 = 0, a3 = 0;
        float b0 = 0, b1 = 0, b2 = 0, b3 = 0;

        // static 2x8-edge chunks per node, pair-interleaved (masked; safe via tail)
        chunk8(s0,     ee0, a0, a1, a2, a3);
        chunk8(s1,     ee1, b0, b1, b2, b3);
        chunk8(s0 + 8, ee0, a0, a1, a2, a3);
        chunk8(s1 + 8, ee1, b0, b1, b2, b3);
        // rare heavy nodes (cn > 16)
        for (int e = s0 + 16; e < ee0; e += 8) chunk8(e, ee0, a0, a1, a2, a3);
        for (int e = s1 + 16; e < ee1; e += 8) chunk8(e, ee1, b0, b1, b2, b3);

        // interleaved cross-quarter reductions for both nodes
        a0 += __shfl_xor(a0, 16, 64); b0 += __shfl_xor(b0, 16, 64);
        a1 += __shfl_xor(a1, 16, 64); b1 += __shfl_xor(b1, 16, 64);
        a2 += __shfl_xor(a2, 16, 64); b2 += __shfl_xor(b2, 16, 64);
        a3 += __shfl_xor(a3, 16, 64); b3 += __shfl_xor(b3, 16, 64);
        a0 += __shfl_xor(a0, 32, 64); b0 += __shfl_xor(b0, 32, 64);
        a1 += __shfl_xor(a1, 32, 64); b1 += __shfl_xor(b1, 32, 64);
        a2 += __shfl_xor(a2, 32, 64); b2 += __shfl_xor(b2, 32, 64);
        a3 += __shfl_xor(a3, 32, 64); b3 += __shfl_xor(b3, 32, 64);

        int node0 = nb + gp, node1 = nb + gp + 1;
        int ni0 = (node0 < N_NODES) ? node0 : 0;
        int ni1 = (node1 < N_NODES) ? node1 : 0;
        if (qd == 0) {
            uint2 xv0 = xr[(size_t)ni0 * 16 + fg];
            uint2 xv1 = xr[(size_t)ni1 * 16 + fg];
            *(uint2*)&sA[wid][gp][4 * fg] = xv0;
            *(uint2*)&sA[wid][gp + 1][4 * fg] = xv1;
        }
        if (qd == 1) {
            float sc0 = -dinv[ni0];   // apply dst-side norm once per node
            float sc1 = -dinv[ni1];
            uint2 p0, p1;
            p0.x = (uint)f2bf(a0 * sc0) | ((uint)f2bf(a1 * sc0) << 16);
            p0.y = (uint)f2bf(a2 * sc0) | ((uint)f2bf(a3 * sc0) << 16);
            p1.x = (uint)f2bf(b0 * sc1) | ((uint)f2bf(b1 * sc1) << 16);
            p1.y = (uint)f2bf(b2 * sc1) | ((uint)f2bf(b3 * sc1) << 16);
            *(uint2*)&sA[wid][gp][64 + 4 * fg] = p0;
            *(uint2*)&sA[wid][gp + 1][64 + 4 * fg] = p1;
        }
    }
    __builtin_amdgcn_wave_barrier();

    const short8* pk8 = (const short8*)pk;
    float4v C[4];
#pragma unroll
    for (int nt = 0; nt < 4; ++nt) {
        float b = bias[nt * 16 + c];
        C[nt] = (float4v){b, b, b, b};
    }
#pragma unroll
    for (int kt = 0; kt < 4; ++kt) {
        short8 af = *(const short8*)&sA[wid][c][kt * 32 + q * 8];
#pragma unroll
        for (int nt = 0; nt < 4; ++nt) {
            short8 bfr = pk8[(kt * 4 + nt) * 64 + lane];
            C[nt] = __builtin_amdgcn_mfma_f32_16x16x32_bf16(af, bfr, C[nt], 0, 0, 0);
        }
    }

#pragma unroll
    for (int nt = 0; nt < 4; ++nt) {
#pragma unroll
        for (int i = 0; i < 4; ++i) {
            int node = nb + q * 4 + i;
            if (node < N_NODES) {
                float v = C[nt][i];
                if (!last) {
                    v = fmaxf(v, 0.0f);
                    out_bf[(size_t)node * NF + nt * 16 + c] = f2bf(v);
                } else {
                    out_f32[(size_t)node * NF + nt * 16 + c] = v;
                }
            }
        }
    }
}

extern "C" void kernel_launch(void* const* d_in, const int* in_sizes, int n_in,
                              void* d_out, int out_size, void* d_ws, size_t ws_size,
                              hipStream_t stream) {
    const int* ei = (const int*)d_in[0];
    const int* row = ei;
    const int* col = ei + N_EDGES;
    const float* emb = (const float*)d_in[1];
    const float* W1_0 = (const float*)d_in[2];
    const float* W1_1 = (const float*)d_in[3];
    const float* b1 = (const float*)d_in[4];
    const float* W2_0 = (const float*)d_in[5];
    const float* W2_1 = (const float*)d_in[6];
    const float* b2 = (const float*)d_in[7];
    float* out = (float*)d_out;

    char* ws = (char*)d_ws;
    int* cnt = (int*)(ws + OFF_CNT);
    int* endp = (int*)(ws + OFF_ENDP);
    float* dinv = (float*)(ws + OFF_DINV);
    int* cur = (int*)(ws + OFF_CUR);
    ushort* pk = (ushort*)(ws + OFF_PKW);
    int* srcs = (int*)(ws + OFF_SRCS);
    ushort* sbinned = (ushort*)(ws + OFF_SBIN);
    int* dbinned = (int*)(ws + OFF_DBIN);
    ushort* emb_bf = (ushort*)(ws + OFF_EMBBF);
    ushort* h_bf = (ushort*)(ws + OFF_HBF);

    hipMemsetAsync(cur, 0, 2 * NBINS * sizeof(int), stream);
    prepsort<<<NBLK + 8 + 3125, 256, 0, stream>>>(W1_0, W1_1, W2_0, W2_1, pk,
                                                  emb, emb_bf, row, col, cur,
                                                  sbinned, dbinned);
    build<<<2 * NBINS, 512, 0, stream>>>(sbinned, dbinned, cur, dinv, cnt, endp, srcs);

    cheb_layer<<<LB2, 128, 0, stream>>>(emb_bf, srcs, dinv, endp, cnt, pk, b1, h_bf, nullptr, 0);
    cheb_layer<<<LB2, 128, 0, stream>>>(h_bf, srcs, dinv, endp, cnt, pk + 8192, b2, nullptr, out, 1);
}